// Round 9
// baseline (21781.718 us; speedup 1.0000x reference)
//
#include <hip/hip_runtime.h>

// Farthest point sampling, B=32, N=32768, npoint=4096.
// R9: 8 blocks per batch (grid=256 = all CUs), 4 pts/thread in registers.
// Cross-block per-step argmax handshake on fresh slots (no reuse/reset races):
//   leader: atomicMax(key[k], pack(dist,idx))          [device-scope RMW]
//           fetch_add(cnt[k], 1, RELEASE, AGENT)
//           poll load(cnt[k], ACQUIRE, AGENT) == 8     [s_sleep backoff]
//           load key[k] -> winner                      [release-seq visible]
// pack = f32bits(dist)<<32 | ~idx  (dist>=0 -> monotone; tie -> smaller idx,
// matching numpy first-occurrence argmax).
// REGULAR launch (graph-capture-safe; R8's hipLaunchCooperativeKernel was
// dropped from the captured graph -> empty replays). Co-residency: grid=256,
// __launch_bounds__(1024,1), 1 block/CU needed, capacity 2 -> all resident,
// no cross-block retirement dependency -> spin cannot deadlock.
// PASSING arithmetic (R6): d = fmaf(dz,dz, fmaf(dx,dx, dy*dy)),
// contract(off), fminf, first-occurrence argmax. Output float32.

#define BATCH  32
#define NPTS   32768
#define NPOINT 4096
#define NBLK   8                  // blocks per batch
#define NT     1024
#define PPB    (NPTS / NBLK)      // 4096 points per block
#define NPT    (PPB / NT)         // 4 points per thread

#define KEY_BYTES ((size_t)BATCH * NPOINT * 8)
#define CNT_BYTES ((size_t)BATCH * NPOINT * 4)
#define WS_NEEDED (KEY_BYTES + CNT_BYTES)

__global__ __launch_bounds__(NT, 1) void fps_multi(
    const float* __restrict__ xyz,
    float* __restrict__ out_idx,
    float* __restrict__ out_xyz,
    unsigned long long* __restrict__ keyArr,   // [BATCH][NPOINT], zeroed
    unsigned int* __restrict__ cntArr)         // [BATCH][NPOINT], zeroed
{
#pragma clang fp contract(off)
    const int g   = blockIdx.x & (BATCH - 1);  // batch (sub-blocks of a batch
    const int j   = blockIdx.x >> 5;           //  share blockIdx%8 -> same XCD)
    const int tid = threadIdx.x;
    const float* base = xyz + (size_t)g * NPTS * 3;

    float px[NPT], py[NPT], pz[NPT], dist[NPT];
#pragma unroll
    for (int i = 0; i < NPT; ++i) {
        const int p = j * PPB + i * NT + tid;
        px[i] = base[p * 3 + 0];
        py[i] = base[p * 3 + 1];
        pz[i] = base[p * 3 + 2];
        dist[i] = 1e10f;
    }

    __shared__ float s_val[16];
    __shared__ int   s_idx[16];
    __shared__ int   s_win;

    unsigned long long* key = keyArr + (size_t)g * NPOINT;
    unsigned int*       cnt = cntArr + (size_t)g * NPOINT;

    int w = 1;   // RAN=False seed
    for (int k = 0; k < NPOINT; ++k) {
        // Same address across lanes -> broadcast load (L2-hot).
        const float cx = base[w * 3 + 0];
        const float cy = base[w * 3 + 1];
        const float cz = base[w * 3 + 2];
        if (j == 0 && tid == 0) {
            out_idx[(size_t)g * NPOINT + k] = (float)w;
            float* o = out_xyz + ((size_t)g * NPOINT + k) * 3;
            o[0] = cx; o[1] = cy; o[2] = cz;
        }
        if (k == NPOINT - 1) break;

        // Local distance update + first-occurrence argmax over my 4 points.
        float best = -1.0f;
        int   bi   = 0x7fffffff;
#pragma unroll
        for (int i = 0; i < NPT; ++i) {
            const float dx = px[i] - cx;
            const float dy = py[i] - cy;
            const float dz = pz[i] - cz;
            const float d  = fmaf(dz, dz, fmaf(dx, dx, dy * dy));
            const float nd = fminf(dist[i], d);
            dist[i] = nd;
            if (nd > best) { best = nd; bi = j * PPB + i * NT + tid; }
        }

        // Wave butterfly argmax; ties -> smaller index.
#pragma unroll
        for (int off = 1; off < 64; off <<= 1) {
            const float ov = __shfl_xor(best, off, 64);
            const int   oi = __shfl_xor(bi,   off, 64);
            if (ov > best || (ov == best && oi < bi)) { best = ov; bi = oi; }
        }
        const int wv = tid >> 6;
        if ((tid & 63) == 0) { s_val[wv] = best; s_idx[wv] = bi; }
        __syncthreads();                  // wave partials ready

        if (tid < 64) {
            float v  = (tid < 16) ? s_val[tid] : -2.0f;
            int   ix = (tid < 16) ? s_idx[tid] : 0x7fffffff;
#pragma unroll
            for (int off = 1; off < 16; off <<= 1) {
                const float ov = __shfl_xor(v,  off, 64);
                const int   oi = __shfl_xor(ix, off, 64);
                if (ov > v || (ov == v && oi < ix)) { v = ov; ix = oi; }
            }
            if (tid == 0) {
                // Cross-block handshake (fresh slot per step).
                const unsigned long long myk =
                    ((unsigned long long)__float_as_uint(v) << 32) |
                    (unsigned int)(~ix);
                atomicMax(&key[k], myk);                       // device scope
                __hip_atomic_fetch_add(&cnt[k], 1u,
                                       __ATOMIC_RELEASE,
                                       __HIP_MEMORY_SCOPE_AGENT);
                while (__hip_atomic_load(&cnt[k],
                                         __ATOMIC_ACQUIRE,
                                         __HIP_MEMORY_SCOPE_AGENT)
                       < (unsigned)NBLK) {
                    __builtin_amdgcn_s_sleep(1);
                }
                const unsigned long long kk =
                    __hip_atomic_load(&key[k], __ATOMIC_RELAXED,
                                      __HIP_MEMORY_SCOPE_AGENT);
                s_win = (int)(~(unsigned int)kk);   // low word = ~idx
            }
        }
        __syncthreads();                  // winner ready
        w = s_win;
    }
}

// ---------- fallback (R7, passing): used only if ws_size too small ----------
#define FB_NPT (NPTS / NT)
#define FB_SMEM (NPTS * 4 + 64 + 64 + 16)

__global__ __launch_bounds__(NT, 1) void fps_single(
    const float* __restrict__ xyz, float* __restrict__ out_idx,
    float* __restrict__ out_xyz)
{
#pragma clang fp contract(off)
    extern __shared__ char smem[];
    float* pz_lds = (float*)smem;
    float* s_val  = (float*)(smem + NPTS * 4);
    int*   s_idx  = (int*)  (smem + NPTS * 4 + 64);
    int*   s_win  = (int*)  (smem + NPTS * 4 + 128);
    const int b = blockIdx.x, tid = threadIdx.x;
    const float* base = xyz + (size_t)b * NPTS * 3;
    float px[FB_NPT], py[FB_NPT], dist[FB_NPT];
#pragma unroll
    for (int i = 0; i < FB_NPT; ++i) {
        const int g = i * NT + tid;
        px[i] = base[g * 3 + 0]; py[i] = base[g * 3 + 1];
        pz_lds[g] = base[g * 3 + 2]; dist[i] = 1e10f;
    }
    __syncthreads();
    int winner = 1;
    for (int k = 0; k < NPOINT; ++k) {
        const float cx = base[winner * 3 + 0];
        const float cy = base[winner * 3 + 1];
        const float cz = base[winner * 3 + 2];
        if (tid == 0) {
            out_idx[(size_t)b * NPOINT + k] = (float)winner;
            float* o = out_xyz + ((size_t)b * NPOINT + k) * 3;
            o[0] = cx; o[1] = cy; o[2] = cz;
        }
        float best = -1.0f; int bi = 0x7fffffff;
#pragma unroll
        for (int c = 0; c < FB_NPT / 8; ++c) {
            float pzv[8];
#pragma unroll
            for (int jj = 0; jj < 8; ++jj)
                pzv[jj] = pz_lds[(c * 8 + jj) * NT + tid];
#pragma unroll
            for (int jj = 0; jj < 8; ++jj) {
                const int i = c * 8 + jj;
                const float dx = px[i] - cx, dy = py[i] - cy,
                            dz = pzv[jj] - cz;
                const float d  = fmaf(dz, dz, fmaf(dx, dx, dy * dy));
                const float nd = fminf(dist[i], d);
                dist[i] = nd;
                if (nd > best) { best = nd; bi = i * NT + tid; }
            }
        }
#pragma unroll
        for (int off = 1; off < 64; off <<= 1) {
            const float ov = __shfl_xor(best, off, 64);
            const int   oi = __shfl_xor(bi,   off, 64);
            if (ov > best || (ov == best && oi < bi)) { best = ov; bi = oi; }
        }
        const int wv = tid >> 6;
        if ((tid & 63) == 0) { s_val[wv] = best; s_idx[wv] = bi; }
        __syncthreads();
        if (tid < 64) {
            float v = (tid < 16) ? s_val[tid] : -2.0f;
            int ix  = (tid < 16) ? s_idx[tid] : 0x7fffffff;
#pragma unroll
            for (int off = 1; off < 16; off <<= 1) {
                const float ov = __shfl_xor(v,  off, 64);
                const int   oi = __shfl_xor(ix, off, 64);
                if (ov > v || (ov == v && oi < ix)) { v = ov; ix = oi; }
            }
            if (tid == 0) *s_win = ix;
        }
        __syncthreads();
        winner = *s_win;
    }
}

extern "C" void kernel_launch(void* const* d_in, const int* in_sizes, int n_in,
                              void* d_out, int out_size, void* d_ws, size_t ws_size,
                              hipStream_t stream) {
    const float* xyz = (const float*)d_in[0];
    float* out = (float*)d_out;
    float* out_idx = out;
    float* out_xyz = out + (size_t)BATCH * NPOINT;

    if (ws_size >= WS_NEEDED) {
        unsigned long long* keyArr = (unsigned long long*)d_ws;
        unsigned int* cntArr = (unsigned int*)((char*)d_ws + KEY_BYTES);
        hipMemsetAsync(d_ws, 0, WS_NEEDED, stream);   // fresh slots each replay

        fps_multi<<<dim3(BATCH * NBLK), dim3(NT), 0, stream>>>(
            xyz, out_idx, out_xyz, keyArr, cntArr);
    } else {
        (void)hipFuncSetAttribute((const void*)fps_single,
                                  hipFuncAttributeMaxDynamicSharedMemorySize,
                                  FB_SMEM);
        fps_single<<<BATCH, NT, FB_SMEM, stream>>>(xyz, out_idx, out_xyz);
    }
}

// Round 10
// 12699.458 us; speedup vs baseline: 1.7152x; 1.7152x over previous
//
#include <hip/hip_runtime.h>

// Farthest point sampling, B=32, N=32768, npoint=4096.
// R10 = R7 topology (1 block/batch, 32 CUs) with per-step overhead attacked:
//  - __launch_bounds__(1024,4): 128-VGPR budget -> px/py/dist (96 floats)
//    stay in arch VGPRs, no v_accvgpr copy traffic (R7 had VGPR_Count=64).
//  - pair ownership g = c*2048 + 2*tid + j: pz reads become ds_read_b64
//    (16 LDS ops/step instead of 32; 2-way bank aliasing = free).
//  - final reduce: 16 wave leaders LDS-atomicMax a packed key
//    (f32bits(dist)<<32 | ~idx) into slot[k&1]; barrier; all threads read
//    winner directly. Alternate slot reset between the two barriers.
//    Ties -> smaller global index (numpy first-occurrence). 2 barriers/step.
// PASSING arithmetic (R6, bit-exact): d = fmaf(dz,dz, fmaf(dx,dx, dy*dy)),
// contract(off), fminf chain, ascending-index strict-> argmax.
// Output float32: [B*NPOINT] idx, [B*NPOINT*3] coords.

#define BATCH  32
#define NPTS   32768
#define NPOINT 4096
#define NT     1024
#define NC     16            // chunks: NPT = NC*2 points per thread
#define SMEM_BYTES (NPTS * 4 + 32)

__global__ __launch_bounds__(NT, 4) void fps_kernel(
    const float* __restrict__ xyz,   // [B, N, 3] float32
    float* __restrict__ out_idx,     // [B, NPOINT]
    float* __restrict__ out_xyz)     // [B, NPOINT, 3]
{
#pragma clang fp contract(off)
    extern __shared__ char smem[];
    float* pz_lds = (float*)smem;                                // NPTS floats
    unsigned long long* s_key = (unsigned long long*)(smem + NPTS * 4); // [2]

    const int b   = blockIdx.x;
    const int tid = threadIdx.x;
    const float* base = xyz + (size_t)b * NPTS * 3;

    float px[NC * 2], py[NC * 2], dist[NC * 2];
#pragma unroll
    for (int c = 0; c < NC; ++c) {
#pragma unroll
        for (int j = 0; j < 2; ++j) {
            const int i = c * 2 + j;
            const int g = c * 2048 + 2 * tid + j;
            px[i] = base[g * 3 + 0];
            py[i] = base[g * 3 + 1];
            pz_lds[g] = base[g * 3 + 2];
            dist[i] = 1e10f;
        }
    }
    if (tid == 0) { s_key[0] = 0ull; s_key[1] = 0ull; }
    __syncthreads();                       // pz_lds + slots ready

    int w = 1;   // RAN=False seed

    for (int k = 0; k < NPOINT; ++k) {
        // Broadcast centroid from global (same addr across lanes, L2-hot).
        const float cx = base[w * 3 + 0];
        const float cy = base[w * 3 + 1];
        const float cz = base[w * 3 + 2];
        if (tid == 0) {
            out_idx[(size_t)b * NPOINT + k] = (float)w;
            float* o = out_xyz + ((size_t)b * NPOINT + k) * 3;
            o[0] = cx; o[1] = cy; o[2] = cz;
        }

        // Distance update + first-occurrence argmax (indices ascend per
        // thread: g = c*2048 + 2*tid + j with c,j ascending).
        float best = -1.0f;
        int   bi   = 0x7fffffff;
#pragma unroll
        for (int c = 0; c < NC; ++c) {
            const float2 pzp =
                *(const float2*)&pz_lds[c * 2048 + 2 * tid];  // ds_read_b64
            const float pzv[2] = { pzp.x, pzp.y };
#pragma unroll
            for (int j = 0; j < 2; ++j) {
                const int i = c * 2 + j;
                const float dx = px[i] - cx;
                const float dy = py[i] - cy;
                const float dz = pzv[j] - cz;
                const float d  = fmaf(dz, dz, fmaf(dx, dx, dy * dy));
                const float nd = fminf(dist[i], d);
                dist[i] = nd;
                if (nd > best) { best = nd; bi = c * 2048 + 2 * tid + j; }
            }
        }

        // Wave (64-lane) butterfly argmax; ties -> smaller index.
#pragma unroll
        for (int off = 1; off < 64; off <<= 1) {
            const float ov = __shfl_xor(best, off, 64);
            const int   oi = __shfl_xor(bi,   off, 64);
            if (ov > best || (ov == best && oi < bi)) { best = ov; bi = oi; }
        }

        // 16 wave leaders -> LDS atomicMax on packed key, slot k&1.
        const int p = k & 1;
        if ((tid & 63) == 0) {
            const unsigned long long myk =
                ((unsigned long long)__float_as_uint(best) << 32) |
                (unsigned int)(~bi);
            atomicMax(&s_key[p], myk);
        }
        __syncthreads();                   // B1: winner key published
        const unsigned long long kk = s_key[p];
        if (tid == 0) s_key[p ^ 1] = 0ull; // reset other slot (used at k+1;
                                           //  last read before B1 of step k-1)
        __syncthreads();                   // B2: reset ordered before k+1 max
        w = (int)(~(unsigned int)kk);      // low word = ~idx
    }
}

extern "C" void kernel_launch(void* const* d_in, const int* in_sizes, int n_in,
                              void* d_out, int out_size, void* d_ws, size_t ws_size,
                              hipStream_t stream) {
    const float* xyz = (const float*)d_in[0];
    float* out = (float*)d_out;
    float* out_idx = out;                              // B*NPOINT floats
    float* out_xyz = out + (size_t)BATCH * NPOINT;     // B*NPOINT*3 floats

    // Opt into >64KB dynamic LDS (runtime call, not captured by graphs).
    (void)hipFuncSetAttribute((const void*)fps_kernel,
                              hipFuncAttributeMaxDynamicSharedMemorySize,
                              SMEM_BYTES);

    fps_kernel<<<BATCH, NT, SMEM_BYTES, stream>>>(xyz, out_idx, out_xyz);
}